// Round 7
// baseline (1101.845 us; speedup 1.0000x reference)
//
#include <hip/hip_runtime.h>

typedef __bf16 bf16;
typedef __bf16 bf16x8 __attribute__((ext_vector_type(8)));
typedef float f32x4 __attribute__((ext_vector_type(4)));
typedef unsigned int u32;

#define NB    2048
#define NM    26
#define NROWS 65536   // (b,k) pairs
#define NJP   28      // 26 j-chunks + 2 zero pad (unconditional prefetch)

__device__ __forceinline__ void gl_lds16(const bf16* g, bf16* l) {
  __builtin_amdgcn_global_load_lds(
      (const __attribute__((address_space(1))) void*)g,
      (__attribute__((address_space(3))) void*)l, 16, 0, 0);
}

__device__ __forceinline__ bf16x8 splat8(u32 p) {
  union { u32 u[4]; bf16x8 v; } s;
  s.u[0] = p; s.u[1] = p; s.u[2] = p; s.u[3] = p;
  return s.v;
}

// ---------------- fused prep: all layout reorders + out-bias init -------------
__global__ __launch_bounds__(256) void prep_all(
    const float* __restrict__ in, const float* __restrict__ W1,
    const float* __restrict__ W2, const float* __restrict__ b2,
    bf16* __restrict__ xb, u32* __restrict__ xbT,
    bf16* __restrict__ w1t, bf16* __restrict__ w2t,
    float* __restrict__ out)
{
  const int bid = blockIdx.x, t = threadIdx.x;
  if (bid < 8192) {                       // xb[(b*32+k)*32+j] = in[b][j][k]
    int e = bid*256 + t;
    int row = e >> 5, j = e & 31;
    float v = (j < NM) ? in[(row >> 5)*(NM*32) + j*32 + (row & 31)] : 0.f;
    xb[e] = (bf16)v;
  } else if (bid < 15360) {               // xbT[j][row] = pair-dup bf16(in[b][j][k])
    int e = (bid-8192)*256 + t;
    int j = e >> 16, row = e & 65535;
    float v = (j < NM) ? in[(row >> 5)*(NM*32) + j*32 + (row & 31)] : 0.f;
    union { bf16 h; unsigned short s; } cv; cv.h = (bf16)v;
    xbT[e] = (u32)cv.s * 0x10001u;
  } else if (bid < 15808) {               // w1t tiles [cs(2)][c(NJP)][r(64)][i(32)]
    int e = (bid-15360)*256 + t;
    int i = e & 31, r = (e >> 5) & 63;
    int rest = e >> 11;
    int c = rest % NJP, cs_idx = rest / NJP;
    int h = cs_idx*64 + r;
    float v = (i < NM && c < NM) ? W1[h*(NM*NM) + i*NM + c] : 0.f;
    w1t[e] = (bf16)v;
  } else if (bid < 17600) {               // w2t tiles [q(8)][j(NJP)][r(64)][c(32)]
    int e = (bid-15808)*256 + t;
    int c = e & 31, r = (e >> 5) & 63;
    int rest = e >> 11;
    int j = rest % NJP, q = rest / NJP;   // q = cs_idx*4 + ii
    int ii = q & 3, cs_idx = q >> 2;
    int h = cs_idx*64 + r, i = ii*32 + c;
    float v = (j < NM) ? W2[h*(128*NM) + i*NM + j] : 0.f;
    w2t[e] = (bf16)v;
  } else {                                // out[b][128+col] = 32*b2[col]
    int e = (bid-17600)*256 + t;
    int b = e >> 7, col = e & 127;
    out[b*256 + 128 + col] = 32.0f * b2[col];
  }
}

// one K-chunk step: barrier; stage chunk J+1 into LDS buf NXT; compute from CUR
#define STEP(CUR, NXT, J) do {                                                 \
  __syncthreads();                                                             \
  gl_lds16(tb + (long)((J)+1)*2048 + t*8, &ldsB[NXT][t*8]);                    \
  _Pragma("unroll")                                                            \
  for (int mi = 0; mi < 4; ++mi) sc[NXT][mi] = sp[((J)+1)*NROWS + mi*16];      \
  bf16x8 bfr[4];                                                               \
  _Pragma("unroll")                                                            \
  for (int ni = 0; ni < 4; ++ni)                                               \
    bfr[ni] = *(const bf16x8*)&ldsB[CUR][ni*512 + fo];                         \
  _Pragma("unroll")                                                            \
  for (int mi = 0; mi < 4; ++mi) {                                             \
    bf16x8 af = xf[mi] * splat8(sc[CUR][mi]);                                  \
    _Pragma("unroll")                                                          \
    for (int ni = 0; ni < 4; ++ni)                                             \
      acc[mi][ni] = __builtin_amdgcn_mfma_f32_16x16x32_bf16(af, bfr[ni],       \
                                                            acc[mi][ni], 0, 0, 0); \
  }                                                                            \
} while (0)

// ---------------- layer 1: block = 256 rows x one cs-half, shared B staging ---
__global__ __launch_bounds__(256, 6) void cin1(
    const bf16* __restrict__ xb, const u32* __restrict__ xbT,
    const bf16* __restrict__ w1t, const float* __restrict__ b1,
    bf16* __restrict__ x1b, float* __restrict__ out)
{
  __shared__ __align__(16) bf16 ldsB[2][2048];
  const int t = threadIdx.x;
  const int lane = t & 63, w = t >> 6;
  const int cs_idx = blockIdx.x & 1, cs = cs_idx * 64;
  const int strip4 = blockIdx.x >> 1;
  const int rowBase = strip4*256 + w*64;
  const int lr = lane & 15, lq = lane >> 4;
  const int fo = lr*32 + lq*8;

  bf16x8 xf[4];
  #pragma unroll
  for (int mi = 0; mi < 4; ++mi)
    xf[mi] = *(const bf16x8*)&xb[(rowBase + mi*16 + lr)*32 + lq*8];

  f32x4 acc[4][4];
  #pragma unroll
  for (int mi=0; mi<4; ++mi)
    #pragma unroll
    for (int ni=0; ni<4; ++ni) acc[mi][ni] = {0.f,0.f,0.f,0.f};

  const bf16* tb = w1t + (long)cs_idx*NJP*2048;
  const u32*  sp = xbT + rowBase + lr;

  u32 sc[2][4];
  gl_lds16(tb + t*8, &ldsB[0][t*8]);          // stage chunk 0
  #pragma unroll
  for (int mi=0; mi<4; ++mi) sc[0][mi] = sp[mi*16];

  for (int jj = 0; jj < 13; ++jj) {
    STEP(0, 1, 2*jj);
    STEP(1, 0, 2*jj + 1);
  }

  float bias[4];
  #pragma unroll
  for (int ni=0; ni<4; ++ni) bias[ni] = b1[cs + ni*16 + lr];
  #pragma unroll
  for (int mi=0; mi<4; ++mi)
    #pragma unroll
    for (int ni=0; ni<4; ++ni) {
      int col = cs + ni*16 + lr;
      #pragma unroll
      for (int r=0; r<4; ++r) {
        int row = rowBase + mi*16 + lq*4 + r;
        x1b[row*128 + col] = (bf16)(acc[mi][ni][r] + bias[ni]);
      }
    }
  #pragma unroll
  for (int half=0; half<2; ++half) {
    int b = (rowBase >> 5) + half;
    #pragma unroll
    for (int ni=0; ni<4; ++ni) {
      float v = 0.f;
      #pragma unroll
      for (int mi=0; mi<2; ++mi)
        #pragma unroll
        for (int r=0; r<4; ++r) v += acc[half*2+mi][ni][r];
      v += __shfl_xor(v, 16, 64);
      v += __shfl_xor(v, 32, 64);
      if (lq == 0) out[b*256 + cs + ni*16 + lr] = v + 32.0f * bias[ni];
    }
  }
}

// ---------------- layer 2: block = 256 rows x one (cs,ii) combo ---------------
// all 4 waves share each 4KB w2t chunk; partial k-sums atomicAdd'ed into out
__global__ __launch_bounds__(256, 6) void cin2(
    const u32* __restrict__ xbT, const bf16* __restrict__ x1b,
    const bf16* __restrict__ w2t, float* __restrict__ out)
{
  __shared__ __align__(16) bf16 ldsB[2][2048];
  const int t = threadIdx.x;
  const int lane = t & 63, w = t >> 6;
  const int q = blockIdx.x & 7;               // q = cs_idx*4 + ii
  const int strip4 = blockIdx.x >> 3;
  const int cs_idx = q >> 2, cs = cs_idx * 64, ii = q & 3;
  const int rowBase = strip4*256 + w*64;
  const int lr = lane & 15, lq = lane >> 4;
  const int fo = lr*32 + lq*8;

  bf16x8 xf[4];
  #pragma unroll
  for (int mi = 0; mi < 4; ++mi)
    xf[mi] = *(const bf16x8*)&x1b[(rowBase + mi*16 + lr)*128 + ii*32 + lq*8];

  f32x4 acc[4][4];
  #pragma unroll
  for (int mi=0; mi<4; ++mi)
    #pragma unroll
    for (int ni=0; ni<4; ++ni) acc[mi][ni] = {0.f,0.f,0.f,0.f};

  const bf16* tb = w2t + (long)q*NJP*2048;
  const u32*  sp = xbT + rowBase + lr;

  u32 sc[2][4];
  gl_lds16(tb + t*8, &ldsB[0][t*8]);          // stage chunk 0
  #pragma unroll
  for (int mi=0; mi<4; ++mi) sc[0][mi] = sp[mi*16];

  for (int jj = 0; jj < 13; ++jj) {
    STEP(0, 1, 2*jj);
    STEP(1, 0, 2*jj + 1);
  }

  // partial k-sums -> atomicAdd into out[b][128+col] (pre-inited with 32*b2)
  #pragma unroll
  for (int half=0; half<2; ++half) {
    int b = (rowBase >> 5) + half;
    #pragma unroll
    for (int ni=0; ni<4; ++ni) {
      float v = 0.f;
      #pragma unroll
      for (int mi=0; mi<2; ++mi)
        #pragma unroll
        for (int r=0; r<4; ++r) v += acc[half*2+mi][ni][r];
      v += __shfl_xor(v, 16, 64);
      v += __shfl_xor(v, 32, 64);
      if (lq == 0) atomicAdd(&out[b*256 + 128 + cs + ni*16 + lr], v);
    }
  }
}

// ---------------- launch ----------------
extern "C" void kernel_launch(void* const* d_in, const int* in_sizes, int n_in,
                              void* d_out, int out_size, void* d_ws, size_t ws_size,
                              hipStream_t stream) {
  const float* in = (const float*)d_in[0];
  const float* W1 = (const float*)d_in[1];
  const float* b1 = (const float*)d_in[2];
  const float* W2 = (const float*)d_in[3];
  const float* b2 = (const float*)d_in[4];
  float* out = (float*)d_out;

  char* ws = (char*)d_ws;
  bf16* xb  = (bf16*)(ws);                 // 65536*32*2  = 4,194,304
  u32*  xbT = (u32*) (ws + 4194304);       // 28*65536*4  = 7,340,032
  bf16* w1t = (bf16*)(ws + 11534336);      // 2*28*2048*2 = 229,376
  bf16* w2t = (bf16*)(ws + 11763712);      // 8*28*2048*2 = 917,504
  bf16* x1b = (bf16*)(ws + 12681216);      // 65536*128*2 = 16,777,216 (end ~29.5 MB)

  prep_all<<<18624, 256, 0, stream>>>(in, W1, W2, b2, xb, xbT, w1t, w2t, out);
  cin1    <<<512,   256, 0, stream>>>(xb, xbT, w1t, b1, x1b, out);
  cin2    <<<2048,  256, 0, stream>>>(xbT, x1b, w2t, out);
}

// Round 8
// 161.511 us; speedup vs baseline: 6.8221x; 6.8221x over previous
//
#include <hip/hip_runtime.h>

typedef __bf16 bf16;
typedef __bf16 bf16x8 __attribute__((ext_vector_type(8)));
typedef float f32x4 __attribute__((ext_vector_type(4)));
typedef unsigned int u32;

#define NB    2048
#define NM    26
#define NROWS 65536   // (b,k) pairs
#define NJP   28      // 26 j-chunks + 2 zero pad (unconditional prefetch)

__device__ __forceinline__ void gl_lds16(const bf16* g, bf16* l) {
  __builtin_amdgcn_global_load_lds(
      (const __attribute__((address_space(1))) void*)g,
      (__attribute__((address_space(3))) void*)l, 16, 0, 0);
}

__device__ __forceinline__ bf16x8 splat8(u32 p) {
  union { u32 u[4]; bf16x8 v; } s;
  s.u[0] = p; s.u[1] = p; s.u[2] = p; s.u[3] = p;
  return s.v;
}

// ---------------- fused prep: all layout reorders + out-bias init -------------
// Weight tiles are stored FRAGMENT-LINEAR: within a 64x32 tile, element
// (r = ni*16+lr, c = lq*8+el) lives at offset ni*512 + lq*128 + lr*8 + el,
// so in-kernel ds_read_b128 fragment reads sweep contiguous 512B runs.
__global__ __launch_bounds__(256) void prep_all(
    const float* __restrict__ in, const float* __restrict__ W1,
    const float* __restrict__ W2, const float* __restrict__ b2,
    bf16* __restrict__ xb, u32* __restrict__ xbT,
    bf16* __restrict__ w1t, bf16* __restrict__ w2t,
    float* __restrict__ out)
{
  const int bid = blockIdx.x, t = threadIdx.x;
  if (bid < 8192) {                       // xb[(b*32+k)*32+j] = in[b][j][k]
    int e = bid*256 + t;
    int row = e >> 5, j = e & 31;
    float v = (j < NM) ? in[(row >> 5)*(NM*32) + j*32 + (row & 31)] : 0.f;
    xb[e] = (bf16)v;
  } else if (bid < 15360) {               // xbT[j][row] = pair-dup bf16(in[b][j][k])
    int e = (bid-8192)*256 + t;
    int j = e >> 16, row = e & 65535;
    float v = (j < NM) ? in[(row >> 5)*(NM*32) + j*32 + (row & 31)] : 0.f;
    union { bf16 h; unsigned short s; } cv; cv.h = (bf16)v;
    xbT[e] = (u32)cv.s * 0x10001u;
  } else if (bid < 15808) {               // w1t tiles [cs(2)][c(NJP)], frag-linear
    int e = (bid-15360)*256 + t;
    int el = e & 7, lr = (e >> 3) & 15, lq = (e >> 7) & 3, ni = (e >> 9) & 3;
    int rest = e >> 11;
    int c = rest % NJP, cs_idx = rest / NJP;
    int h = cs_idx*64 + ni*16 + lr;       // row within 128
    int i = lq*8 + el;                    // col within 32
    float v = (i < NM && c < NM) ? W1[h*(NM*NM) + i*NM + c] : 0.f;
    w1t[e] = (bf16)v;
  } else if (bid < 17600) {               // w2t tiles [q(8)][j(NJP)], frag-linear
    int e = (bid-15808)*256 + t;
    int el = e & 7, lr = (e >> 3) & 15, lq = (e >> 7) & 3, ni = (e >> 9) & 3;
    int rest = e >> 11;
    int j = rest % NJP, q = rest / NJP;   // q = cs_idx*4 + ii
    int ii = q & 3, cs_idx = q >> 2;
    int h = cs_idx*64 + ni*16 + lr, i = ii*32 + lq*8 + el;
    float v = (j < NM) ? W2[h*(128*NM) + i*NM + j] : 0.f;
    w2t[e] = (bf16)v;
  } else {                                // out[b][128+col] = 32*b2[col]
    int e = (bid-17600)*256 + t;
    int b = e >> 7, col = e & 127;
    out[b*256 + 128 + col] = 32.0f * b2[col];
  }
}

// one K-chunk step: barrier; stage chunk J+1 into LDS buf NXT; compute from CUR
#define STEP(CUR, NXT, J) do {                                                 \
  __syncthreads();                                                             \
  gl_lds16(tb + (long)((J)+1)*2048 + t*8, &ldsB[NXT][t*8]);                    \
  _Pragma("unroll")                                                            \
  for (int mi = 0; mi < 4; ++mi) sc[NXT][mi] = sp[((J)+1)*NROWS + mi*16];      \
  bf16x8 bfr[4];                                                               \
  _Pragma("unroll")                                                            \
  for (int ni = 0; ni < 4; ++ni)                                               \
    bfr[ni] = *(const bf16x8*)&ldsB[CUR][ni*512 + fo];                         \
  _Pragma("unroll")                                                            \
  for (int mi = 0; mi < 4; ++mi) {                                             \
    bf16x8 af = xf[mi] * splat8(sc[CUR][mi]);                                  \
    _Pragma("unroll")                                                          \
    for (int ni = 0; ni < 4; ++ni)                                             \
      acc[mi][ni] = __builtin_amdgcn_mfma_f32_16x16x32_bf16(af, bfr[ni],       \
                                                            acc[mi][ni], 0, 0, 0); \
  }                                                                            \
} while (0)

// ---------------- layer 1: block = 256 rows x one cs-half, shared B staging ---
__global__ __launch_bounds__(256, 4) void cin1(
    const bf16* __restrict__ xb, const u32* __restrict__ xbT,
    const bf16* __restrict__ w1t, const float* __restrict__ b1,
    bf16* __restrict__ x1b, float* __restrict__ out)
{
  __shared__ __align__(16) bf16 ldsB[2][2048];
  const int t = threadIdx.x;
  const int lane = t & 63, w = t >> 6;
  const int cs_idx = blockIdx.x & 1, cs = cs_idx * 64;
  const int strip4 = blockIdx.x >> 1;
  const int rowBase = strip4*256 + w*64;
  const int lr = lane & 15, lq = lane >> 4;
  const int fo = lq*128 + lr*8;               // fragment-linear offset

  bf16x8 xf[4];
  #pragma unroll
  for (int mi = 0; mi < 4; ++mi)
    xf[mi] = *(const bf16x8*)&xb[(rowBase + mi*16 + lr)*32 + lq*8];

  f32x4 acc[4][4];
  #pragma unroll
  for (int mi=0; mi<4; ++mi)
    #pragma unroll
    for (int ni=0; ni<4; ++ni) acc[mi][ni] = {0.f,0.f,0.f,0.f};

  const bf16* tb = w1t + (long)cs_idx*NJP*2048;
  const u32*  sp = xbT + rowBase + lr;

  u32 sc[2][4];
  gl_lds16(tb + t*8, &ldsB[0][t*8]);          // stage chunk 0
  #pragma unroll
  for (int mi=0; mi<4; ++mi) sc[0][mi] = sp[mi*16];

  for (int jj = 0; jj < 13; ++jj) {
    STEP(0, 1, 2*jj);
    STEP(1, 0, 2*jj + 1);
  }

  float bias[4];
  #pragma unroll
  for (int ni=0; ni<4; ++ni) bias[ni] = b1[cs + ni*16 + lr];
  #pragma unroll
  for (int mi=0; mi<4; ++mi)
    #pragma unroll
    for (int ni=0; ni<4; ++ni) {
      int col = cs + ni*16 + lr;
      #pragma unroll
      for (int r=0; r<4; ++r) {
        int row = rowBase + mi*16 + lq*4 + r;
        x1b[row*128 + col] = (bf16)(acc[mi][ni][r] + bias[ni]);
      }
    }
  #pragma unroll
  for (int half=0; half<2; ++half) {
    int b = (rowBase >> 5) + half;
    #pragma unroll
    for (int ni=0; ni<4; ++ni) {
      float v = 0.f;
      #pragma unroll
      for (int mi=0; mi<2; ++mi)
        #pragma unroll
        for (int r=0; r<4; ++r) v += acc[half*2+mi][ni][r];
      v += __shfl_xor(v, 16, 64);
      v += __shfl_xor(v, 32, 64);
      if (lq == 0) out[b*256 + cs + ni*16 + lr] = v + 32.0f * bias[ni];
    }
  }
}

// ---------------- layer 2: block = 256 rows x one (cs,ii) combo ---------------
// all 4 waves share each 4KB w2t chunk; partial k-sums atomicAdd'ed into out
__global__ __launch_bounds__(256, 4) void cin2(
    const u32* __restrict__ xbT, const bf16* __restrict__ x1b,
    const bf16* __restrict__ w2t, float* __restrict__ out)
{
  __shared__ __align__(16) bf16 ldsB[2][2048];
  const int t = threadIdx.x;
  const int lane = t & 63, w = t >> 6;
  const int q = blockIdx.x & 7;               // q = cs_idx*4 + ii
  const int strip4 = blockIdx.x >> 3;
  const int cs_idx = q >> 2, cs = cs_idx * 64, ii = q & 3;
  const int rowBase = strip4*256 + w*64;
  const int lr = lane & 15, lq = lane >> 4;
  const int fo = lq*128 + lr*8;               // fragment-linear offset

  bf16x8 xf[4];
  #pragma unroll
  for (int mi = 0; mi < 4; ++mi)
    xf[mi] = *(const bf16x8*)&x1b[(rowBase + mi*16 + lr)*128 + ii*32 + lq*8];

  f32x4 acc[4][4];
  #pragma unroll
  for (int mi=0; mi<4; ++mi)
    #pragma unroll
    for (int ni=0; ni<4; ++ni) acc[mi][ni] = {0.f,0.f,0.f,0.f};

  const bf16* tb = w2t + (long)q*NJP*2048;
  const u32*  sp = xbT + rowBase + lr;

  u32 sc[2][4];
  gl_lds16(tb + t*8, &ldsB[0][t*8]);          // stage chunk 0
  #pragma unroll
  for (int mi=0; mi<4; ++mi) sc[0][mi] = sp[mi*16];

  for (int jj = 0; jj < 13; ++jj) {
    STEP(0, 1, 2*jj);
    STEP(1, 0, 2*jj + 1);
  }

  // partial k-sums -> atomicAdd into out[b][128+col] (pre-inited with 32*b2)
  #pragma unroll
  for (int half=0; half<2; ++half) {
    int b = (rowBase >> 5) + half;
    #pragma unroll
    for (int ni=0; ni<4; ++ni) {
      float v = 0.f;
      #pragma unroll
      for (int mi=0; mi<2; ++mi)
        #pragma unroll
        for (int r=0; r<4; ++r) v += acc[half*2+mi][ni][r];
      v += __shfl_xor(v, 16, 64);
      v += __shfl_xor(v, 32, 64);
      if (lq == 0) atomicAdd(&out[b*256 + 128 + cs + ni*16 + lr], v);
    }
  }
}

// ---------------- launch ----------------
extern "C" void kernel_launch(void* const* d_in, const int* in_sizes, int n_in,
                              void* d_out, int out_size, void* d_ws, size_t ws_size,
                              hipStream_t stream) {
  const float* in = (const float*)d_in[0];
  const float* W1 = (const float*)d_in[1];
  const float* b1 = (const float*)d_in[2];
  const float* W2 = (const float*)d_in[3];
  const float* b2 = (const float*)d_in[4];
  float* out = (float*)d_out;

  char* ws = (char*)d_ws;
  bf16* xb  = (bf16*)(ws);                 // 65536*32*2  = 4,194,304
  u32*  xbT = (u32*) (ws + 4194304);       // 28*65536*4  = 7,340,032
  bf16* w1t = (bf16*)(ws + 11534336);      // 2*28*2048*2 = 229,376
  bf16* w2t = (bf16*)(ws + 11763712);      // 8*28*2048*2 = 917,504
  bf16* x1b = (bf16*)(ws + 12681216);      // 65536*128*2 = 16,777,216 (end ~29.5 MB)

  prep_all<<<18624, 256, 0, stream>>>(in, W1, W2, b2, xb, xbT, w1t, w2t, out);
  cin1    <<<512,   256, 0, stream>>>(xb, xbT, w1t, b1, x1b, out);
  cin2    <<<2048,  256, 0, stream>>>(xbT, x1b, w2t, out);
}

// Round 9
// 124.240 us; speedup vs baseline: 8.8687x; 1.3000x over previous
//
#include <hip/hip_runtime.h>

typedef __bf16 bf16;
typedef __bf16 bf16x8 __attribute__((ext_vector_type(8)));
typedef __bf16 bf16x4 __attribute__((ext_vector_type(4)));
typedef float f32x4 __attribute__((ext_vector_type(4)));
typedef unsigned int u32;

#define NB    2048
#define NM    26
#define NROWS 65536   // (b,k) pairs
#define NJP   27      // 26 j-chunks + 1 pad (unconditional prefetch)

__device__ __forceinline__ void gl_lds16(const bf16* g, bf16* l) {
  __builtin_amdgcn_global_load_lds(
      (const __attribute__((address_space(1))) void*)g,
      (__attribute__((address_space(3))) void*)l, 16, 0, 0);
}

__device__ __forceinline__ bf16x8 splat8(u32 p) {
  union { u32 u[4]; bf16x8 v; } s;
  s.u[0] = p; s.u[1] = p; s.u[2] = p; s.u[3] = p;
  return s.v;
}

// ---------------- fused prep: all layout reorders -----------------------------
// Weight tiles are FRAGMENT-LINEAR: in a 64x32 tile, element (r=ni*16+lr,
// c=lq*8+el) lives at ni*512 + lq*128 + lr*8 + el.
__global__ __launch_bounds__(256) void prep_all(
    const float* __restrict__ in, const float* __restrict__ W1,
    const float* __restrict__ W2,
    bf16* __restrict__ xb, u32* __restrict__ xbT,
    bf16* __restrict__ w1t, bf16* __restrict__ w2t2)
{
  const int bid = blockIdx.x, t = threadIdx.x;
  if (bid < 8192) {                       // xb[(b*32+k)*32+j] = in[b][j][k]
    int e = bid*256 + t;
    int row = e >> 5, j = e & 31;
    float v = (j < NM) ? in[(row >> 5)*(NM*32) + j*32 + (row & 31)] : 0.f;
    xb[e] = (bf16)v;
  } else if (bid < 15104) {               // xbT[j][row] = pair-dup bf16, j<27
    int e = (bid-8192)*256 + t;
    int j = e >> 16, row = e & 65535;
    float v = (j < NM) ? in[(row >> 5)*(NM*32) + j*32 + (row & 31)] : 0.f;
    union { bf16 h; unsigned short s; } cv; cv.h = (bf16)v;
    xbT[e] = (u32)cv.s * 0x10001u;
  } else if (bid < 15536) {               // w1t tiles [cs(2)][c(NJP)], frag-linear
    int e = (bid-15104)*256 + t;
    int el = e & 7, lr = (e >> 3) & 15, lq = (e >> 7) & 3, ni = (e >> 9) & 3;
    int rest = e >> 11;
    int c = rest % NJP, cs_idx = rest / NJP;
    int h = cs_idx*64 + ni*16 + lr;
    int i = lq*8 + el;
    float v = (i < NM && c < NM) ? W1[h*(NM*NM) + i*NM + c] : 0.f;
    w1t[e] = (bf16)v;
  } else {                                // w2t2 tiles [cs(2)][kc(130)], frag-linear
    int e = (bid-15536)*256 + t;          // flatK = kc*32 + c  (kc=i, c=j)
    int el = e & 7, lr = (e >> 3) & 15, lq = (e >> 7) & 3, ni = (e >> 9) & 3;
    int rest = e >> 11;                   // [0, 260)
    int kc = rest % 130, cs_idx = rest / 130;
    int h = cs_idx*64 + ni*16 + lr;
    int c = lq*8 + el;
    float v = (kc < 128 && c < NM) ? W2[h*(128*NM) + kc*NM + c] : 0.f;
    w2t2[e] = (bf16)v;
  }
}

// one K-chunk step: barrier; stage chunk J+1 into LDS buf NXT; compute from CUR
#define STEP(CUR, NXT, J) do {                                                 \
  __syncthreads();                                                             \
  gl_lds16(tb + (long)((J)+1)*2048 + t*8, &ldsB[NXT][t*8]);                    \
  _Pragma("unroll")                                                            \
  for (int mi = 0; mi < 4; ++mi) sc[NXT][mi] = sp[((J)+1)*NROWS + mi*16];      \
  bf16x8 bfr[4];                                                               \
  _Pragma("unroll")                                                            \
  for (int ni = 0; ni < 4; ++ni)                                               \
    bfr[ni] = *(const bf16x8*)&ldsB[CUR][ni*512 + fo];                         \
  _Pragma("unroll")                                                            \
  for (int mi = 0; mi < 4; ++mi) {                                             \
    bf16x8 af = xf[mi] * splat8(sc[CUR][mi]);                                  \
    _Pragma("unroll")                                                          \
    for (int ni = 0; ni < 4; ++ni)                                             \
      acc[mi][ni] = __builtin_amdgcn_mfma_f32_16x16x32_bf16(af, bfr[ni],       \
                                                            acc[mi][ni], 0, 0, 0); \
  }                                                                            \
} while (0)

// ---------------- layer 1: block = 256 rows x one cs-half ---------------------
// writes x1T[b][i][k] (bf16, +bias) and out[:, 0:128]
__global__ __launch_bounds__(256, 4) void cin1(
    const bf16* __restrict__ xb, const u32* __restrict__ xbT,
    const bf16* __restrict__ w1t, const float* __restrict__ b1,
    bf16* __restrict__ x1T, float* __restrict__ out)
{
  __shared__ __align__(16) bf16 ldsB[2][2048];
  const int t = threadIdx.x;
  const int lane = t & 63, w = t >> 6;
  const int cs_idx = blockIdx.x & 1, cs = cs_idx * 64;
  const int strip4 = blockIdx.x >> 1;
  const int rowBase = strip4*256 + w*64;
  const int lr = lane & 15, lq = lane >> 4;
  const int fo = lq*128 + lr*8;

  bf16x8 xf[4];
  #pragma unroll
  for (int mi = 0; mi < 4; ++mi)
    xf[mi] = *(const bf16x8*)&xb[(rowBase + mi*16 + lr)*32 + lq*8];

  f32x4 acc[4][4];
  #pragma unroll
  for (int mi=0; mi<4; ++mi)
    #pragma unroll
    for (int ni=0; ni<4; ++ni) acc[mi][ni] = {0.f,0.f,0.f,0.f};

  const bf16* tb = w1t + (long)cs_idx*NJP*2048;
  const u32*  sp = xbT + rowBase + lr;

  u32 sc[2][4];
  gl_lds16(tb + t*8, &ldsB[0][t*8]);          // stage chunk 0
  #pragma unroll
  for (int mi=0; mi<4; ++mi) sc[0][mi] = sp[mi*16];

  for (int jj = 0; jj < 13; ++jj) {
    STEP(0, 1, 2*jj);
    STEP(1, 0, 2*jj + 1);
  }

  float bias[4];
  #pragma unroll
  for (int ni=0; ni<4; ++ni) bias[ni] = b1[cs + ni*16 + lr];
  // x1T[b][col][k] packed 4-k stores (8 B per lane)
  #pragma unroll
  for (int mi=0; mi<4; ++mi)
    #pragma unroll
    for (int ni=0; ni<4; ++ni) {
      int col = cs + ni*16 + lr;
      int rb  = mi*16 + lq*4;               // 0..60, mult of 4
      int b   = (rowBase + rb) >> 5;
      int k0  = rb & 31;
      bf16x4 pk;
      #pragma unroll
      for (int r=0; r<4; ++r) pk[r] = (bf16)(acc[mi][ni][r] + bias[ni]);
      *(bf16x4*)&x1T[((long)b*128 + col)*32 + k0] = pk;
    }
  #pragma unroll
  for (int half=0; half<2; ++half) {
    int b = (rowBase >> 5) + half;
    #pragma unroll
    for (int ni=0; ni<4; ++ni) {
      float v = 0.f;
      #pragma unroll
      for (int mi=0; mi<2; ++mi)
        #pragma unroll
        for (int r=0; r<4; ++r) v += acc[half*2+mi][ni][r];
      v += __shfl_xor(v, 16, 64);
      v += __shfl_xor(v, 32, 64);
      if (lq == 0) out[b*256 + cs + ni*16 + lr] = v + 32.0f * bias[ni];
    }
  }
}

// ---------------- G kernel: G[b][i*32+j] = sum_k x1[b,i,k]*x0[b,j,k] ----------
// per wave: one (b, m-half); A = x1T (k-contig), B = original input (k-contig)
__global__ __launch_bounds__(256) void gkern(
    const float* __restrict__ in, const bf16* __restrict__ x1T, bf16* __restrict__ G)
{
  const int t = threadIdx.x;
  const int lane = t & 63, w = t >> 6;
  const int gw = blockIdx.x*4 + w;
  const int b = gw >> 1, mh = gw & 1;
  const int lr = lane & 15, lq = lane >> 4;

  bf16x8 bfr[2];
  #pragma unroll
  for (int nt = 0; nt < 2; ++nt) {
    int j = nt*16 + lr;
    bf16x8 v;
    #pragma unroll
    for (int e=0; e<8; ++e) v[e] = (bf16)0.f;
    if (j < NM) {
      const float* src = in + b*(NM*32) + j*32 + lq*8;
      f32x4 a = *(const f32x4*)src, c = *(const f32x4*)(src+4);
      #pragma unroll
      for (int e=0; e<4; ++e) { v[e] = (bf16)a[e]; v[4+e] = (bf16)c[e]; }
    }
    bfr[nt] = v;
  }
  #pragma unroll
  for (int m4 = 0; m4 < 4; ++m4) {
    int mt = mh*4 + m4;
    bf16x8 af = *(const bf16x8*)&x1T[((long)b*128 + mt*16 + lr)*32 + lq*8];
    #pragma unroll
    for (int nt = 0; nt < 2; ++nt) {
      f32x4 z = {0.f,0.f,0.f,0.f};
      f32x4 g = __builtin_amdgcn_mfma_f32_16x16x32_bf16(af, bfr[nt], z, 0, 0, 0);
      #pragma unroll
      for (int r = 0; r < 4; ++r) {
        int i = mt*16 + lq*4 + r;
        G[(long)b*4096 + i*32 + nt*16 + lr] = (bf16)g[r];
      }
    }
  }
}

// ---------------- gemm2: p[s][b][h] = partial sum_K G[b][K]*W2p[h][K] ---------
// M=2048 b, N=128 h, K=4096 flat (kc=i chunks of 32); split-K x8, reg K-loop
#define STEPG(CUR, NXT, KN) do {                                               \
  _Pragma("unroll")                                                            \
  for (int mi = 0; mi < 2; ++mi)                                               \
    A[NXT][mi] = *(const bf16x8*)(Ab + (long)(mi*16+lr)*4096 + (KN)*32);       \
  _Pragma("unroll")                                                            \
  for (int ni = 0; ni < 4; ++ni)                                               \
    B[NXT][ni] = *(const bf16x8*)(tb + (long)(KN)*2048 + ni*512);              \
  _Pragma("unroll")                                                            \
  for (int mi = 0; mi < 2; ++mi)                                               \
    _Pragma("unroll")                                                          \
    for (int ni = 0; ni < 4; ++ni)                                             \
      acc[mi][ni] = __builtin_amdgcn_mfma_f32_16x16x32_bf16(A[CUR][mi],        \
                                  B[CUR][ni], acc[mi][ni], 0, 0, 0);           \
} while (0)

__global__ __launch_bounds__(256, 4) void gemm2(
    const bf16* __restrict__ G, const bf16* __restrict__ w2t2, float* __restrict__ p)
{
  const int t = threadIdx.x;
  const int lane = t & 63, w = t >> 6;
  const int s = blockIdx.x >> 5;              // 8 splits
  const int q32 = blockIdx.x & 31;
  const int tile = q32*4 + w;                 // 0..127
  const int cs_idx = tile & 1, ms = tile >> 1;
  const int rowB = ms*32;
  const int lr = lane & 15, lq = lane >> 4;
  const int fo = lq*128 + lr*8;
  const int kc0 = s*16;

  const bf16* Ab = G + (long)rowB*4096 + lq*8;
  const bf16* tb = w2t2 + (long)cs_idx*130*2048 + fo;

  f32x4 acc[2][4];
  #pragma unroll
  for (int mi=0; mi<2; ++mi)
    #pragma unroll
    for (int ni=0; ni<4; ++ni) acc[mi][ni] = {0.f,0.f,0.f,0.f};

  bf16x8 A[2][2], B[2][4];
  #pragma unroll
  for (int mi=0; mi<2; ++mi)
    A[0][mi] = *(const bf16x8*)(Ab + (long)(mi*16+lr)*4096 + kc0*32);
  #pragma unroll
  for (int ni=0; ni<4; ++ni)
    B[0][ni] = *(const bf16x8*)(tb + (long)kc0*2048 + ni*512);

  for (int jj = 0; jj < 8; ++jj) {
    STEPG(0, 1, kc0 + 2*jj + 1);
    STEPG(1, 0, kc0 + 2*jj + 2);
  }

  #pragma unroll
  for (int mi=0; mi<2; ++mi)
    #pragma unroll
    for (int ni=0; ni<4; ++ni) {
      int h = cs_idx*64 + ni*16 + lr;
      #pragma unroll
      for (int r=0; r<4; ++r) {
        int b = rowB + mi*16 + lq*4 + r;
        p[((long)s*NB + b)*128 + h] = acc[mi][ni][r];
      }
    }
}

// ---------------- combine: out[b][128+h] = 32*b2[h] + sum_s p -----------------
__global__ __launch_bounds__(256) void combine(
    const float* __restrict__ p, const float* __restrict__ b2, float* __restrict__ out)
{
  int idx = blockIdx.x * 256 + threadIdx.x;   // [0, NB*128)
  int b = idx >> 7, h = idx & 127;
  float v = 32.0f * b2[h];
  #pragma unroll
  for (int s=0; s<8; ++s) v += p[((long)s*NB + b)*128 + h];
  out[b*256 + 128 + h] = v;
}

// ---------------- launch ----------------
extern "C" void kernel_launch(void* const* d_in, const int* in_sizes, int n_in,
                              void* d_out, int out_size, void* d_ws, size_t ws_size,
                              hipStream_t stream) {
  const float* in = (const float*)d_in[0];
  const float* W1 = (const float*)d_in[1];
  const float* b1 = (const float*)d_in[2];
  const float* W2 = (const float*)d_in[3];
  const float* b2 = (const float*)d_in[4];
  float* out = (float*)d_out;

  char* ws = (char*)d_ws;
  bf16* x1T  = (bf16*)(ws);                 // 65536*128*2   = 16,777,216
  bf16* w2t2 = (bf16*)(ws + 16777216);      // 2*130*2048*2  = 1,064,960  -> 17,842,176
  bf16* xb   = (bf16*)(ws + 17842176);      // 4,194,304               -> 22,036,480  [dead after cin1]
  u32*  xbT  = (u32*) (ws + 22036480);      // 27*65536*4 = 7,077,888  -> 29,114,368  [dead after cin1]
  bf16* w1t  = (bf16*)(ws + 29114368);      // 2*27*2048*2 = 221,184   -> 29,335,552  [dead after cin1]
  bf16* G    = (bf16*)(ws + 17842176);      // 16,777,216 (+4K slack) over dead xb/xbT/w1t -> 34,623,488
  float* p   = (float*)(ws);                // 8*2048*128*4 = 8,388,608 over dead x1T

  prep_all<<<17616, 256, 0, stream>>>(in, W1, W2, xb, xbT, w1t, w2t2);
  cin1    <<<512,   256, 0, stream>>>(xb, xbT, w1t, b1, x1T, out);
  gkern   <<<1024,  256, 0, stream>>>(in, x1T, G);
  gemm2   <<<256,   256, 0, stream>>>(G, w2t2, p);
  combine <<<1024,  256, 0, stream>>>(p, b2, out);
}

// Round 10
// 112.563 us; speedup vs baseline: 9.7887x; 1.1037x over previous
//
#include <hip/hip_runtime.h>

typedef __bf16 bf16;
typedef __bf16 bf16x8 __attribute__((ext_vector_type(8)));
typedef __bf16 bf16x4 __attribute__((ext_vector_type(4)));
typedef float f32x4 __attribute__((ext_vector_type(4)));
typedef unsigned int u32;

#define NB    2048
#define NM    26
#define NJP   27      // 26 K-chunks + 1 zero pad (unconditional weight prefetch)

__device__ __forceinline__ void gl_lds16(const bf16* g, bf16* l) {
  __builtin_amdgcn_global_load_lds(
      (const __attribute__((address_space(1))) void*)g,
      (__attribute__((address_space(3))) void*)l, 16, 0, 0);
}

__device__ __forceinline__ bf16x8 splat8(u32 p) {
  union { u32 u[4]; bf16x8 v; } s;
  s.u[0] = p; s.u[1] = p; s.u[2] = p; s.u[3] = p;
  return s.v;
}

__device__ __forceinline__ u32 dup16(float v) {
  union { bf16 h; unsigned short s; } cv; cv.h = (bf16)v;
  return (u32)cv.s * 0x10001u;
}

// ---------------- fused prep: xb + frag-linear weight tiles -------------------
// Weight tiles FRAGMENT-LINEAR: in a 64x32 tile, element (r=ni*16+lr,
// c=lq*8+el) lives at ni*512 + lq*128 + lr*8 + el.
__global__ __launch_bounds__(256) void prep_all(
    const float* __restrict__ in, const float* __restrict__ W1,
    const float* __restrict__ W2,
    bf16* __restrict__ xb, bf16* __restrict__ w1t, bf16* __restrict__ w2t2)
{
  const int bid = blockIdx.x, t = threadIdx.x;
  if (bid < 8192) {                       // xb[(b*32+k)*32+j] = in[b][j][k]
    int e = bid*256 + t;
    int row = e >> 5, j = e & 31;
    float v = (j < NM) ? in[(row >> 5)*(NM*32) + j*32 + (row & 31)] : 0.f;
    xb[e] = (bf16)v;
  } else if (bid < 8624) {                // w1t tiles [cs(2)][c(NJP)], frag-linear
    int e = (bid-8192)*256 + t;
    int el = e & 7, lr = (e >> 3) & 15, lq = (e >> 7) & 3, ni = (e >> 9) & 3;
    int rest = e >> 11;
    int c = rest % NJP, cs_idx = rest / NJP;
    int h = cs_idx*64 + ni*16 + lr;
    int i = lq*8 + el;
    float v = (i < NM && c < NM) ? W1[h*(NM*NM) + i*NM + c] : 0.f;
    w1t[e] = (bf16)v;
  } else {                                // w2t2 tiles [cs(2)][kc(130)], frag-linear
    int e = (bid-8624)*256 + t;           // flatK = kc*32 + c  (kc=i, c=j)
    int el = e & 7, lr = (e >> 3) & 15, lq = (e >> 7) & 3, ni = (e >> 9) & 3;
    int rest = e >> 11;                   // [0, 260)
    int kc = rest % 130, cs_idx = rest / 130;
    int h = cs_idx*64 + ni*16 + lr;
    int c = lq*8 + el;
    float v = (kc < 128 && c < NM) ? W2[h*(128*NM) + kc*NM + c] : 0.f;
    w2t2[e] = (bf16)v;
  }
}

// one K-chunk step: barrier; stage chunk J+1 into LDS buf NXT; A-scalars
// prefetched straight from `in` (64B-contiguous per mi); compute from CUR.
#define STEP(CUR, NXT, J) do {                                                 \
  __syncthreads();                                                             \
  gl_lds16(tb + (long)((J)+1)*2048 + t*8, &ldsB[NXT][t*8]);                    \
  { int jn = ((J)+1 > 25) ? 25 : (J)+1;  /* chunk-26 weights are zero */       \
    sc[NXT][0] = dup16(spA[jn*32]);      sc[NXT][1] = dup16(spA[jn*32 + 16]);  \
    sc[NXT][2] = dup16(spB[jn*32]);      sc[NXT][3] = dup16(spB[jn*32 + 16]); }\
  bf16x8 bfr[4];                                                               \
  _Pragma("unroll")                                                            \
  for (int ni = 0; ni < 4; ++ni)                                               \
    bfr[ni] = *(const bf16x8*)&ldsB[CUR][ni*512 + fo];                         \
  _Pragma("unroll")                                                            \
  for (int mi = 0; mi < 4; ++mi) {                                             \
    bf16x8 af = xf[mi] * splat8(sc[CUR][mi]);                                  \
    _Pragma("unroll")                                                          \
    for (int ni = 0; ni < 4; ++ni)                                             \
      acc[mi][ni] = __builtin_amdgcn_mfma_f32_16x16x32_bf16(af, bfr[ni],       \
                                                            acc[mi][ni], 0, 0, 0); \
  }                                                                            \
} while (0)

// ---------------- layer 1 + fused G: block = 256 rows x one cs-half -----------
// K-loop computes x1 (acc, C-layout); epilogue writes out[:,0:128], transposes
// x1 through wave-private LDS into A-layout, and emits
// G[b][i*32+j] = sum_k x1[b,i,k]*x0[b,j,k]  for i in this block's cs-half.
__global__ __launch_bounds__(256, 4) void cin1G(
    const float* __restrict__ in, const bf16* __restrict__ xb,
    const bf16* __restrict__ w1t, const float* __restrict__ b1,
    bf16* __restrict__ G, float* __restrict__ out)
{
  __shared__ __align__(16) bf16 ldsB[2][2048];
  __shared__ __align__(16) bf16 ldsT[4][64*72];   // wave-private x1^T tiles
  const int t = threadIdx.x;
  const int lane = t & 63, w = t >> 6;
  const int cs_idx = blockIdx.x & 1, cs = cs_idx * 64;
  const int strip4 = blockIdx.x >> 1;
  const int rowBase = strip4*256 + w*64;
  const int lr = lane & 15, lq = lane >> 4;
  const int fo = lq*128 + lr*8;
  const int b0 = rowBase >> 5;                    // wave covers batches b0, b0+1

  const float* spA = in + (long)b0*(NM*32) + lr;  // + j*32 (+16 for k-high)
  const float* spB = spA + NM*32;

  bf16x8 xf[4];
  #pragma unroll
  for (int mi = 0; mi < 4; ++mi)
    xf[mi] = *(const bf16x8*)&xb[(rowBase + mi*16 + lr)*32 + lq*8];

  f32x4 acc[4][4];
  #pragma unroll
  for (int mi=0; mi<4; ++mi)
    #pragma unroll
    for (int ni=0; ni<4; ++ni) acc[mi][ni] = {0.f,0.f,0.f,0.f};

  const bf16* tb = w1t + (long)cs_idx*NJP*2048;

  u32 sc[2][4];
  gl_lds16(tb + t*8, &ldsB[0][t*8]);              // stage chunk 0
  sc[0][0] = dup16(spA[0]);  sc[0][1] = dup16(spA[16]);
  sc[0][2] = dup16(spB[0]);  sc[0][3] = dup16(spB[16]);

  for (int jj = 0; jj < 13; ++jj) {
    STEP(0, 1, 2*jj);
    STEP(1, 0, 2*jj + 1);
  }

  float bias[4];
  #pragma unroll
  for (int ni=0; ni<4; ++ni) bias[ni] = b1[cs + ni*16 + lr];

  // out[b][0:128] = k-sum of x1 + 32*bias
  #pragma unroll
  for (int half=0; half<2; ++half) {
    int b = b0 + half;
    #pragma unroll
    for (int ni=0; ni<4; ++ni) {
      float v = 0.f;
      #pragma unroll
      for (int mi=0; mi<2; ++mi)
        #pragma unroll
        for (int r=0; r<4; ++r) v += acc[half*2+mi][ni][r];
      v += __shfl_xor(v, 16, 64);
      v += __shfl_xor(v, 32, 64);
      if (lq == 0) out[b*256 + cs + ni*16 + lr] = v + 32.0f * bias[ni];
    }
  }

  // x1 (C-layout) -> wave-private LDS [i_local][k_local], row stride 72
  bf16* T = &ldsT[w][0];
  #pragma unroll
  for (int mi=0; mi<4; ++mi)
    #pragma unroll
    for (int ni=0; ni<4; ++ni) {
      bf16x4 pk;
      #pragma unroll
      for (int r=0; r<4; ++r) pk[r] = (bf16)(acc[mi][ni][r] + bias[ni]);
      *(bf16x4*)&T[(ni*16+lr)*72 + mi*16 + lq*4] = pk;
    }
  // no barrier: each wave reads only its own tile (compiler orders via lgkmcnt)

  #pragma unroll
  for (int h = 0; h < 2; ++h) {
    const int b = b0 + h;
    bf16x8 bg[2];                               // x0[j][k] B-frags from `in`
    #pragma unroll
    for (int nt = 0; nt < 2; ++nt) {
      int j = nt*16 + lr;
      bf16x8 v;
      #pragma unroll
      for (int e=0; e<8; ++e) v[e] = (bf16)0.f;
      if (j < NM) {
        const float* src = in + (long)b*(NM*32) + j*32 + lq*8;
        f32x4 a = *(const f32x4*)src, c = *(const f32x4*)(src+4);
        #pragma unroll
        for (int e=0; e<4; ++e) { v[e] = (bf16)a[e]; v[4+e] = (bf16)c[e]; }
      }
      bg[nt] = v;
    }
    #pragma unroll
    for (int mt = 0; mt < 4; ++mt) {
      bf16x8 ag = *(const bf16x8*)&T[(mt*16+lr)*72 + h*32 + lq*8];
      #pragma unroll
      for (int nt = 0; nt < 2; ++nt) {
        f32x4 z = {0.f,0.f,0.f,0.f};
        f32x4 g = __builtin_amdgcn_mfma_f32_16x16x32_bf16(ag, bg[nt], z, 0, 0, 0);
        #pragma unroll
        for (int r = 0; r < 4; ++r)
          G[(long)b*4096 + (cs + mt*16 + lq*4 + r)*32 + nt*16 + lr] = (bf16)g[r];
      }
    }
  }
}

// ---------------- gemm2: p[s][b][h] = partial sum_K G[b][K]*W2p[h][K] ---------
// M=2048 b, N=128 h, K=4096 flat (kc=i chunks of 32); split-K x8, reg K-loop
#define STEPG(CUR, NXT, KN) do {                                               \
  _Pragma("unroll")                                                            \
  for (int mi = 0; mi < 2; ++mi)                                               \
    A[NXT][mi] = *(const bf16x8*)(Ab + (long)(mi*16+lr)*4096 + (KN)*32);       \
  _Pragma("unroll")                                                            \
  for (int ni = 0; ni < 4; ++ni)                                               \
    B[NXT][ni] = *(const bf16x8*)(tb + (long)(KN)*2048 + ni*512);              \
  _Pragma("unroll")                                                            \
  for (int mi = 0; mi < 2; ++mi)                                               \
    _Pragma("unroll")                                                          \
    for (int ni = 0; ni < 4; ++ni)                                             \
      acc[mi][ni] = __builtin_amdgcn_mfma_f32_16x16x32_bf16(A[CUR][mi],        \
                                  B[CUR][ni], acc[mi][ni], 0, 0, 0);           \
} while (0)

__global__ __launch_bounds__(256, 4) void gemm2(
    const bf16* __restrict__ G, const bf16* __restrict__ w2t2, float* __restrict__ p)
{
  const int t = threadIdx.x;
  const int lane = t & 63, w = t >> 6;
  const int s = blockIdx.x >> 5;              // 8 splits
  const int q32 = blockIdx.x & 31;
  const int tile = q32*4 + w;                 // 0..127
  const int cs_idx = tile & 1, ms = tile >> 1;
  const int rowB = ms*32;
  const int lr = lane & 15, lq = lane >> 4;
  const int fo = lq*128 + lr*8;
  const int kc0 = s*16;

  const bf16* Ab = G + (long)rowB*4096 + lq*8;
  const bf16* tb = w2t2 + (long)cs_idx*130*2048 + fo;

  f32x4 acc[2][4];
  #pragma unroll
  for (int mi=0; mi<2; ++mi)
    #pragma unroll
    for (int ni=0; ni<4; ++ni) acc[mi][ni] = {0.f,0.f,0.f,0.f};

  bf16x8 A[2][2], B[2][4];
  #pragma unroll
  for (int mi=0; mi<2; ++mi)
    A[0][mi] = *(const bf16x8*)(Ab + (long)(mi*16+lr)*4096 + kc0*32);
  #pragma unroll
  for (int ni=0; ni<4; ++ni)
    B[0][ni] = *(const bf16x8*)(tb + (long)kc0*2048 + ni*512);

  for (int jj = 0; jj < 8; ++jj) {
    STEPG(0, 1, kc0 + 2*jj + 1);
    STEPG(1, 0, kc0 + 2*jj + 2);
  }

  #pragma unroll
  for (int mi=0; mi<2; ++mi)
    #pragma unroll
    for (int ni=0; ni<4; ++ni) {
      int h = cs_idx*64 + ni*16 + lr;
      #pragma unroll
      for (int r=0; r<4; ++r) {
        int b = rowB + mi*16 + lq*4 + r;
        p[((long)s*NB + b)*128 + h] = acc[mi][ni][r];
      }
    }
}

// ---------------- combine: out[b][128+h] = 32*b2[h] + sum_s p -----------------
__global__ __launch_bounds__(256) void combine(
    const float* __restrict__ p, const float* __restrict__ b2, float* __restrict__ out)
{
  int idx = blockIdx.x * 256 + threadIdx.x;   // [0, NB*128)
  int b = idx >> 7, h = idx & 127;
  float v = 32.0f * b2[h];
  #pragma unroll
  for (int s=0; s<8; ++s) v += p[((long)s*NB + b)*128 + h];
  out[b*256 + 128 + h] = v;
}

// ---------------- launch ----------------
extern "C" void kernel_launch(void* const* d_in, const int* in_sizes, int n_in,
                              void* d_out, int out_size, void* d_ws, size_t ws_size,
                              hipStream_t stream) {
  const float* in = (const float*)d_in[0];
  const float* W1 = (const float*)d_in[1];
  const float* b1 = (const float*)d_in[2];
  const float* W2 = (const float*)d_in[3];
  const float* b2 = (const float*)d_in[4];
  float* out = (float*)d_out;

  char* ws = (char*)d_ws;
  bf16* xb   = (bf16*)(ws);                 // 65536*32*2   = 4,194,304
  bf16* w1t  = (bf16*)(ws + 4194304);       // 2*27*2048*2  = 221,184   -> 4,415,488
  bf16* w2t2 = (bf16*)(ws + 4415488);       // 2*130*2048*2 = 1,064,960 -> 5,480,448
  bf16* G    = (bf16*)(ws + 5480448);       // 2048*4096*2  = 16,777,216-> 22,257,664
  float* p   = (float*)(ws + 22257664);     // 8*2048*128*4 = 8,388,608 -> 30,646,272

  prep_all<<<10704, 256, 0, stream>>>(in, W1, W2, xb, w1t, w2t2);
  cin1G   <<<512,   256, 0, stream>>>(in, xb, w1t, b1, G, out);
  gemm2   <<<256,   256, 0, stream>>>(G, w2t2, p);
  combine <<<1024,  256, 0, stream>>>(p, b2, out);
}

// Round 11
// 106.412 us; speedup vs baseline: 10.3545x; 1.0578x over previous
//
#include <hip/hip_runtime.h>

typedef __bf16 bf16;
typedef __bf16 bf16x8 __attribute__((ext_vector_type(8)));
typedef __bf16 bf16x4 __attribute__((ext_vector_type(4)));
typedef float f32x4 __attribute__((ext_vector_type(4)));
typedef unsigned int u32;

#define NB    2048
#define NM    26
#define NJP   27      // 26 K-chunks + 1 zero pad (unconditional weight prefetch)

__device__ __forceinline__ void gl_lds16(const bf16* g, bf16* l) {
  __builtin_amdgcn_global_load_lds(
      (const __attribute__((address_space(1))) void*)g,
      (__attribute__((address_space(3))) void*)l, 16, 0, 0);
}

__device__ __forceinline__ bf16x8 splat8(u32 p) {
  union { u32 u[4]; bf16x8 v; } s;
  s.u[0] = p; s.u[1] = p; s.u[2] = p; s.u[3] = p;
  return s.v;
}

__device__ __forceinline__ u32 dup16(float v) {
  union { bf16 h; unsigned short s; } cv; cv.h = (bf16)v;
  return (u32)cv.s * 0x10001u;
}

// ---------------- fused prep: frag-linear weight tiles + out bias init --------
// Weight tiles FRAGMENT-LINEAR: in a 64x32 tile, element (r=ni*16+lr,
// c=lq*8+el) lives at ni*512 + lq*128 + lr*8 + el.
__global__ __launch_bounds__(256) void prep_all(
    const float* __restrict__ W1, const float* __restrict__ W2,
    const float* __restrict__ b2,
    bf16* __restrict__ w1t, bf16* __restrict__ w2t2, float* __restrict__ out)
{
  const int bid = blockIdx.x, t = threadIdx.x;
  if (bid < 432) {                        // w1t tiles [cs(2)][c(NJP)], frag-linear
    int e = bid*256 + t;
    int el = e & 7, lr = (e >> 3) & 15, lq = (e >> 7) & 3, ni = (e >> 9) & 3;
    int rest = e >> 11;
    int c = rest % NJP, cs_idx = rest / NJP;
    int h = cs_idx*64 + ni*16 + lr;
    int i = lq*8 + el;
    float v = (i < NM && c < NM) ? W1[h*(NM*NM) + i*NM + c] : 0.f;
    w1t[e] = (bf16)v;
  } else if (bid < 2512) {                // w2t2 tiles [cs(2)][kc(130)], frag-linear
    int e = (bid-432)*256 + t;            // flatK = kc*32 + c  (kc=i, c=j)
    int el = e & 7, lr = (e >> 3) & 15, lq = (e >> 7) & 3, ni = (e >> 9) & 3;
    int rest = e >> 11;                   // [0, 260)
    int kc = rest % 130, cs_idx = rest / 130;
    int h = cs_idx*64 + ni*16 + lr;
    int c = lq*8 + el;
    float v = (kc < 128 && c < NM) ? W2[h*(128*NM) + kc*NM + c] : 0.f;
    w2t2[e] = (bf16)v;
  } else {                                // out[b][128+h] = 32*b2[h]
    int e = (bid-2512)*256 + t;           // [0, NB*128)
    int b = e >> 7, h = e & 127;
    out[b*256 + 128 + h] = 32.0f * b2[h];
  }
}

// one K-chunk step: barrier; stage chunk J+1 into LDS buf NXT; A-scalars
// prefetched straight from `in` (broadcast 64B run); compute from CUR.
#define STEP(CUR, NXT, J) do {                                                 \
  __syncthreads();                                                             \
  gl_lds16(tb + (long)((J)+1)*2048 + t*8, &ldsB[NXT][t*8]);                    \
  { int jn = ((J)+1 > 25) ? 25 : (J)+1;  /* chunk-26 weights are zero */       \
    sc[NXT][0] = dup16(spw[jn*32]);                                            \
    sc[NXT][1] = dup16(spw[jn*32 + 16]); }                                     \
  bf16x8 bfr[4];                                                               \
  _Pragma("unroll")                                                            \
  for (int ni = 0; ni < 4; ++ni)                                               \
    bfr[ni] = *(const bf16x8*)&ldsB[CUR][ni*512 + fo];                         \
  _Pragma("unroll")                                                            \
  for (int mi = 0; mi < 2; ++mi) {                                             \
    bf16x8 af = xf[mi] * splat8(sc[CUR][mi]);                                  \
    _Pragma("unroll")                                                          \
    for (int ni = 0; ni < 4; ++ni)                                             \
      acc[mi][ni] = __builtin_amdgcn_mfma_f32_16x16x32_bf16(af, bfr[ni],       \
                                                            acc[mi][ni], 0, 0, 0); \
  }                                                                            \
} while (0)

// ---------------- layer 1 + fused G: wave = 1 batch (32 rows) x one cs-half ---
// K-loop computes x1 (C-layout acc); epilogue writes out[:,0:128], transposes
// x1 through wave-private LDS, and emits G2 in gemm2's tiled layout:
// G2[(ms*512 + k8)*32 + mloc][8] where flatK = i*32+j, k8 = flatK>>3.
__global__ __launch_bounds__(256, 4) void cin1G(
    const float* __restrict__ in, const bf16* __restrict__ w1t,
    const float* __restrict__ b1, bf16* __restrict__ G2, float* __restrict__ out)
{
  __shared__ __align__(16) bf16 ldsB[2][2048];
  __shared__ __align__(16) bf16 ldsT[4][64*36];   // wave-private x1^T [i64][k32+pad]
  const int t = threadIdx.x;
  const int lane = t & 63, w = t >> 6;
  const int cs_idx = blockIdx.x & 1, cs = cs_idx * 64;
  const int strip = blockIdx.x >> 1;
  const int bw = strip*4 + w;                     // this wave's batch
  const int lr = lane & 15, lq = lane >> 4;
  const int fo = lq*128 + lr*8;

  const float* bin = in + (long)bw*(NM*32);
  const float* spw = bin + lr;                    // + j*32 + mi*16 (k = mi*16+lr)

  // x0 A-frags direct from in: xf[mi][e] = x0[bw][j=lq*8+e][k=mi*16+lr]
  bf16x8 xf[2];
  #pragma unroll
  for (int mi = 0; mi < 2; ++mi)
    #pragma unroll
    for (int e = 0; e < 8; ++e) {
      int j = lq*8 + e;
      xf[mi][e] = (bf16)((j < NM) ? bin[j*32 + mi*16 + lr] : 0.f);
    }

  f32x4 acc[2][4];
  #pragma unroll
  for (int mi=0; mi<2; ++mi)
    #pragma unroll
    for (int ni=0; ni<4; ++ni) acc[mi][ni] = {0.f,0.f,0.f,0.f};

  const bf16* tb = w1t + (long)cs_idx*NJP*2048;

  u32 sc[2][2];
  gl_lds16(tb + t*8, &ldsB[0][t*8]);              // stage chunk 0
  sc[0][0] = dup16(spw[0]);  sc[0][1] = dup16(spw[16]);

  for (int jj = 0; jj < 13; ++jj) {
    STEP(0, 1, 2*jj);
    STEP(1, 0, 2*jj + 1);
  }

  float bias[4];
  #pragma unroll
  for (int ni=0; ni<4; ++ni) bias[ni] = b1[cs + ni*16 + lr];

  // out[bw][0:128] = k-sum of x1 + 32*bias
  #pragma unroll
  for (int ni=0; ni<4; ++ni) {
    float v = 0.f;
    #pragma unroll
    for (int mi=0; mi<2; ++mi)
      #pragma unroll
      for (int r=0; r<4; ++r) v += acc[mi][ni][r];
    v += __shfl_xor(v, 16, 64);
    v += __shfl_xor(v, 32, 64);
    if (lq == 0) out[bw*256 + cs + ni*16 + lr] = v + 32.0f * bias[ni];
  }

  // x1 (C-layout) -> wave-private LDS [i_local][k], row stride 36
  bf16* T = &ldsT[w][0];
  #pragma unroll
  for (int mi=0; mi<2; ++mi)
    #pragma unroll
    for (int ni=0; ni<4; ++ni) {
      bf16x4 pk;
      #pragma unroll
      for (int r=0; r<4; ++r) pk[r] = (bf16)(acc[mi][ni][r] + bias[ni]);
      *(bf16x4*)&T[(ni*16+lr)*36 + mi*16 + lq*4] = pk;
    }
  // no barrier: each wave reads only its own tile (lgkmcnt ordering)

  // B-frags: x0[j][k] from in
  bf16x8 bg[2];
  #pragma unroll
  for (int nt = 0; nt < 2; ++nt) {
    int j = nt*16 + lr;
    bf16x8 v;
    #pragma unroll
    for (int e=0; e<8; ++e) v[e] = (bf16)0.f;
    if (j < NM) {
      const float* src = bin + j*32 + lq*8;
      f32x4 a = *(const f32x4*)src, c = *(const f32x4*)(src+4);
      #pragma unroll
      for (int e=0; e<4; ++e) { v[e] = (bf16)a[e]; v[4+e] = (bf16)c[e]; }
    }
    bg[nt] = v;
  }
  // G-MFMAs + tiled G2 stores
  const long gbase = (long)(bw >> 5)*131072 + (bw & 31)*8;
  #pragma unroll
  for (int mt = 0; mt < 4; ++mt) {
    bf16x8 ag = *(const bf16x8*)&T[(mt*16+lr)*36 + lq*8];
    #pragma unroll
    for (int nt = 0; nt < 2; ++nt) {
      f32x4 z = {0.f,0.f,0.f,0.f};
      f32x4 g = __builtin_amdgcn_mfma_f32_16x16x32_bf16(ag, bg[nt], z, 0, 0, 0);
      const int jh = nt*2 + (lr >> 3), jl = lr & 7;
      #pragma unroll
      for (int r = 0; r < 4; ++r) {
        int i = cs + mt*16 + lq*4 + r;
        G2[gbase + (long)(i*4 + jh)*256 + jl] = (bf16)g[r];
      }
    }
  }
}

// ---------------- gemm2: out[b][128+h] += sum_K G[b][K]*W2p[h][K] -------------
// M=2048 b (tiles of 32), N=128 h, K=4096 flat; split-K x8; atomics into out.
#define STEPG(CUR, NXT, KN) do {                                               \
  _Pragma("unroll")                                                            \
  for (int mi = 0; mi < 2; ++mi)                                               \
    A[NXT][mi] = *(const bf16x8*)(Ab + (long)(KN)*1024 + mi*128);              \
  _Pragma("unroll")                                                            \
  for (int ni = 0; ni < 4; ++ni)                                               \
    B[NXT][ni] = *(const bf16x8*)(tb + (long)(KN)*2048 + ni*512);              \
  _Pragma("unroll")                                                            \
  for (int mi = 0; mi < 2; ++mi)                                               \
    _Pragma("unroll")                                                          \
    for (int ni = 0; ni < 4; ++ni)                                             \
      acc[mi][ni] = __builtin_amdgcn_mfma_f32_16x16x32_bf16(A[CUR][mi],        \
                                  B[CUR][ni], acc[mi][ni], 0, 0, 0);           \
} while (0)

__global__ __launch_bounds__(256, 4) void gemm2(
    const bf16* __restrict__ G2, const bf16* __restrict__ w2t2, float* __restrict__ out)
{
  const int t = threadIdx.x;
  const int lane = t & 63, w = t >> 6;
  const int s = blockIdx.x >> 5;              // 8 splits
  const int q32 = blockIdx.x & 31;
  const int tile = q32*4 + w;                 // 0..127
  const int cs_idx = tile & 1, ms = tile >> 1;
  const int lr = lane & 15, lq = lane >> 4;
  const int fo = lq*128 + lr*8;
  const int kc0 = s*16;

  const bf16* Ab = G2 + ((long)(ms*512 + lq)*32 + lr)*8;
  const bf16* tb = w2t2 + (long)cs_idx*130*2048 + fo;

  f32x4 acc[2][4];
  #pragma unroll
  for (int mi=0; mi<2; ++mi)
    #pragma unroll
    for (int ni=0; ni<4; ++ni) acc[mi][ni] = {0.f,0.f,0.f,0.f};

  bf16x8 A[2][2], B[2][4];
  #pragma unroll
  for (int mi=0; mi<2; ++mi)
    A[0][mi] = *(const bf16x8*)(Ab + (long)kc0*1024 + mi*128);
  #pragma unroll
  for (int ni=0; ni<4; ++ni)
    B[0][ni] = *(const bf16x8*)(tb + (long)kc0*2048 + ni*512);

  for (int jj = 0; jj < 8; ++jj) {
    STEPG(0, 1, kc0 + 2*jj + 1);
    STEPG(1, 0, kc0 + 2*jj + 2);
  }

  #pragma unroll
  for (int mi=0; mi<2; ++mi)
    #pragma unroll
    for (int ni=0; ni<4; ++ni) {
      int h = cs_idx*64 + ni*16 + lr;
      #pragma unroll
      for (int r=0; r<4; ++r) {
        int b = ms*32 + mi*16 + lq*4 + r;
        atomicAdd(&out[b*256 + 128 + h], acc[mi][ni][r]);
      }
    }
}

// ---------------- launch ----------------
extern "C" void kernel_launch(void* const* d_in, const int* in_sizes, int n_in,
                              void* d_out, int out_size, void* d_ws, size_t ws_size,
                              hipStream_t stream) {
  const float* in = (const float*)d_in[0];
  const float* W1 = (const float*)d_in[1];
  const float* b1 = (const float*)d_in[2];
  const float* W2 = (const float*)d_in[3];
  const float* b2 = (const float*)d_in[4];
  float* out = (float*)d_out;

  char* ws = (char*)d_ws;
  bf16* w1t  = (bf16*)(ws);                 // 2*27*2048*2  = 221,184
  bf16* w2t2 = (bf16*)(ws + 1048576);       // 2*130*2048*2 = 1,064,960
  bf16* G2   = (bf16*)(ws + 4194304);       // 2048*4096*2  = 16,777,216 (end ~21 MB)

  prep_all<<<3536, 256, 0, stream>>>(W1, W2, b2, w1t, w2t2, out);
  cin1G   <<<1024, 256, 0, stream>>>(in, w1t, b1, G2, out);
  gemm2   <<<256,  256, 0, stream>>>(G2, w2t2, out);
}